// Round 14
// baseline (1297.807 us; speedup 1.0000x reference)
//
#include <hip/hip_runtime.h>

typedef unsigned short ushort_t;
typedef unsigned int uint_t;
typedef unsigned long long u64_t;
typedef unsigned short us8 __attribute__((ext_vector_type(8)));

constexpr int B_ = 8, N_ = 8192, S_ = 1024, K_ = 32;
constexpr int M_ = B_ * S_ * K_;          // 262144
constexpr float R2_ = 0.04f;
constexpr float EPS_ = 1e-5f;

// ---------- helpers ----------
__device__ __forceinline__ float bf2f(ushort_t u) {
    union { uint_t i; float f; } v; v.i = ((uint_t)u) << 16; return v.f;
}
__device__ __forceinline__ ushort_t f2bf(float f) {
    union { float f; uint_t i; } v; v.f = f;
    uint_t i = v.i;
    uint_t r = (i + 0x7FFFu + ((i >> 16) & 1u)) >> 16;   // RNE
    return (ushort_t)r;
}

// f32 DPP max helper (2 inst/stage). bound_ctrl=true -> OOB lanes read 0,
// safe because all reduced values are >= 0.
template<int C> __device__ __forceinline__ float dmaxf(float v) {
    int o = __builtin_amdgcn_mov_dpp(__float_as_int(v), C, 0xf, 0xf, true);
    return fmaxf(v, __int_as_float(o));
}

// ---------- 1. fused: FPS (blocks 0..7) + transpose (8..263) + wt/zero (264) ----------
// FPS: thread t owns points [8t,8t+8) => lane order == index order == wave
// order. Per step: per-wave f32 DPP max -> readlane -> ballot; the wave's
// winner lane packs (value_bits<<32 | complement_index) and LDS-atomicMax's
// into skey[s]; ONE barrier; all threads read skey[s] -> argmax (max value,
// lowest index on tie == jnp.argmax first occurrence). Distances computed in
// the exact reference association order, unfused.
__global__ __launch_bounds__(1024)
void fps_fused(const float* __restrict__ xyz, const float* __restrict__ pts,
               const float* __restrict__ w0, const float* __restrict__ w1,
               const float* __restrict__ w2,
               float* __restrict__ nxyz, float* __restrict__ out0,
               ushort_t* __restrict__ ptT, float* __restrict__ wt,
               float* __restrict__ stats) {
    __shared__ __align__(16) char smem[131072 + 4096 + 8192];
    const int bx = blockIdx.x, t = threadIdx.x;

    if (bx >= 8) {
        if (bx == 264) {
            // zero stats + transpose weights W[co][ci] -> WT[ci][co]
            if (t < 768) stats[t] = 0.0f;
#pragma unroll
            for (int l = 0; l < 3; ++l) {
                const float* w = l == 0 ? w0 : (l == 1 ? w1 : w2);
                int CI = (l == 0) ? 67 : 64;
                int CO = (l == 2) ? 128 : 64;
                float* dst = wt + (l == 0 ? 0 : (l == 1 ? 67 * 64 : 67 * 64 + 64 * 64));
                for (int i = t; i < CI * CO; i += 1024) {
                    int c = i / CO, o = i % CO;
                    dst[c * CO + o] = w[o * CI + c];
                }
            }
            return;
        }
        // transpose: 4 tiles per block (group g handles tile tau)
        int g = t >> 8, lt = t & 255;
        int tau = (bx - 8) * 4 + g;
        int b = tau >> 7, n0 = (tau & 127) * 64;
        int tc = lt & 63, tr = lt >> 6;
        ushort_t* tile = (ushort_t*)(smem + g * 8448);   // 64*66*2 B
        const float* src = pts + (size_t)b * 64 * N_;
#pragma unroll
        for (int i = 0; i < 16; ++i) {
            int c = i * 4 + tr;
            tile[c * 66 + tc] = f2bf(src[(size_t)c * N_ + n0 + tc]);
        }
        __syncthreads();
#pragma unroll
        for (int i = 0; i < 16; ++i) {
            int nr = i * 4 + tr;
            ptT[((size_t)b * N_ + n0 + nr) * 64 + tc] = tile[tc * 66 + nr];
        }
        return;
    }

    // ---------------- FPS path ----------------
    constexpr int T = 1024, P = N_ / T;    // 8 points per thread
    const int b = bx;
    const int lane = t & 63;
    const float* X = xyz + (size_t)b * 3 * N_;

    float4* sxyz = (float4*)smem;                    // 128 KB
    int*    sidx = (int*)(smem + 131072);            // 4 KB
    u64_t*  skey = (u64_t*)(smem + 131072 + 4096);   // 8 KB

    // coalesced global -> LDS; zero per-step key slots
#pragma unroll
    for (int i = 0; i < P; ++i) {
        int n = t + i * T;
        sxyz[n] = make_float4(X[n], X[N_ + n], X[2 * N_ + n], 0.0f);
    }
    skey[t] = 0ull;                        // T == S_
    if (t == 0) sidx[0] = 0;
    __syncthreads();

    // chunked re-read, rotated to cut bank conflicts 64-way -> 8-way
    float px[P], py[P], pz[P], dist[P];
#pragma unroll
    for (int i = 0; i < P; ++i) {
        int j = (i + t) & (P - 1);
        float4 v = sxyz[t * P + j];
        px[j] = v.x; py[j] = v.y; pz[j] = v.z;
        dist[j] = 1e10f;
    }
    float4 cc = sxyz[0];
    float cx = cc.x, cy = cc.y, cz = cc.z;

    for (int s = 0; s < S_; ++s) {
        // exact reference order: ((dx*dx + dy*dy) + dz*dz), unfused
#pragma unroll
        for (int i = 0; i < P; ++i) {
            float dx = __fsub_rn(px[i], cx);
            float dy = __fsub_rn(py[i], cy);
            float dz = __fsub_rn(pz[i], cz);
            float d = __fadd_rn(__fadd_rn(__fmul_rn(dx, dx), __fmul_rn(dy, dy)), __fmul_rn(dz, dz));
            dist[i] = fminf(dist[i], d);
        }
        // in-thread tree max (value only)
        float a0 = fmaxf(dist[0], dist[4]);
        float a1 = fmaxf(dist[1], dist[5]);
        float a2 = fmaxf(dist[2], dist[6]);
        float a3 = fmaxf(dist[3], dist[7]);
        float lmax = fmaxf(fmaxf(a0, a1), fmaxf(a2, a3));
        // wave max via DPP, result in lane 63; broadcast via readlane
        float m = lmax;
        m = dmaxf<0x111>(m);   // row_shr:1
        m = dmaxf<0x112>(m);   // row_shr:2
        m = dmaxf<0x114>(m);   // row_shr:4
        m = dmaxf<0x118>(m);   // row_shr:8
        m = dmaxf<0x142>(m);   // row_bcast:15
        m = dmaxf<0x143>(m);   // row_bcast:31
        float wmax = __int_as_float(__builtin_amdgcn_readlane(__float_as_int(m), 63));
        // wave's winner lane (lowest lane holding wmax) publishes packed key
        u64_t bal = __ballot(lmax == wmax);
        int L = __builtin_ctzll(bal);
        if (lane == L) {
            int fi = 0;
#pragma unroll
            for (int i = P - 1; i >= 0; --i)
                if (dist[i] == wmax) fi = i;               // lowest i wins
            u64_t key = ((u64_t)(uint_t)__float_as_int(wmax) << 32)
                      | (uint_t)(N_ - 1 - (t * P + fi));   // complement idx
            atomicMax(&skey[s], key);                      // ds_max_u64
        }
        __syncthreads();                   // single barrier per step
        u64_t k = skey[s];
        int far = N_ - 1 - (int)(uint_t)k;
        if (t == 0 && s + 1 < S_) sidx[s + 1] = far;
        float4 c = sxyz[far];              // single b128 LDS broadcast
        cx = c.x; cy = c.y; cz = c.z;
    }

    // fused gather: nxyz + output 0 straight from LDS
    __syncthreads();
    {
        int s = t;                             // T == S_
        int idx = sidx[s];
        float4 c = sxyz[idx];
        size_t base = ((size_t)b * S_ + s) * 3;
        nxyz[base + 0] = c.x; nxyz[base + 1] = c.y; nxyz[base + 2] = c.z;
        out0[((size_t)b * 3 + 0) * S_ + s] = c.x;
        out0[((size_t)b * 3 + 1) * S_ + s] = c.y;
        out0[((size_t)b * 3 + 2) * S_ + s] = c.z;
    }
}

// ---------- 3. ball query: one wave per query, ordered ballot compaction ----------
__global__ __launch_bounds__(256)
void ballq_kernel(const float* __restrict__ xyz, const float* __restrict__ nxyz,
                  int* __restrict__ gi) {
    int wid = (blockIdx.x * 256 + threadIdx.x) >> 6;
    int lane = threadIdx.x & 63;
    if (wid >= B_ * S_) return;
    int b = wid / S_;
    const float* X = xyz + (size_t)b * 3 * N_;
    float nx = nxyz[(size_t)wid * 3 + 0];
    float ny = nxyz[(size_t)wid * 3 + 1];
    float nz = nxyz[(size_t)wid * 3 + 2];
    float snew = __fadd_rn(__fadd_rn(__fmul_rn(nx, nx), __fmul_rn(ny, ny)), __fmul_rn(nz, nz));
    int cnt = 0; int firstn = 0;
    int* out = gi + (size_t)wid * K_;
    for (int c0 = 0; c0 < N_; c0 += 64) {
        int n = c0 + lane;
        float xx = X[n], xy = X[N_ + n], xz = X[2 * N_ + n];
        float sxn = __fadd_rn(__fadd_rn(__fmul_rn(xx, xx), __fmul_rn(xy, xy)), __fmul_rn(xz, xz));
        float dot = __fadd_rn(__fadd_rn(__fmul_rn(nx, xx), __fmul_rn(ny, xy)), __fmul_rn(nz, xz));
        float sq = __fsub_rn(__fadd_rn(snew, sxn), __fmul_rn(2.0f, dot));
        bool inr = !(sq > R2_);
        unsigned long long mask = __ballot(inr);
        if (cnt == 0 && mask) firstn = c0 + __builtin_ctzll(mask);
        int rank = __popcll(mask & ((1ull << lane) - 1ull));
        if (inr && cnt + rank < K_) out[cnt + rank] = n;
        cnt += (int)__popcll(mask);
        if (cnt >= K_) break;
    }
    if (cnt < K_ && lane >= cnt && lane < K_) out[lane] = firstn;
}

// ---------- 6a. layer 1: fused gather + fused stats ----------
__global__ __launch_bounds__(256)
void layer1_kernel(const ushort_t* __restrict__ ptT,
                   const float* __restrict__ xyz,
                   const float* __restrict__ nxyz,
                   const int* __restrict__ gi,
                   const float* __restrict__ WT,     // [67][64]
                   const float* __restrict__ bias,   // [64]
                   ushort_t* __restrict__ y,         // [M][64]
                   float* __restrict__ sums) {       // [64]=sum, [128+..]=sumsq
    constexpr int RP = 72;                 // padded row (ushorts), 144 B = 9*16
    __shared__ ushort_t sb[256 * RP];      // 36 KB
    __shared__ float ps[128], pq[128];
    int tid = threadIdx.x;
    int m = blockIdx.x * 256 + tid;
    float acc[64];
#pragma unroll
    for (int o = 0; o < 64; ++o) acc[o] = bias[o];

    int idx = gi[m];
    int b = m >> 15;                       // m / (S*K)
    const ushort_t* row = ptT + ((size_t)b * N_ + idx) * 64;
#pragma unroll
    for (int c8 = 0; c8 < 8; ++c8) {
        us8 v = *reinterpret_cast<const us8*>(row + c8 * 8);
#pragma unroll
        for (int j = 0; j < 8; ++j) {
            int c = c8 * 8 + j;
            float h = bf2f(v[j]);
            const float* wr = WT + (size_t)c * 64;
#pragma unroll
            for (int o = 0; o < 64; ++o) acc[o] = fmaf(h, wr[o], acc[o]);
        }
    }
    int s = (m >> 5) & (S_ - 1);
    const float* X = xyz + (size_t)b * 3 * N_;
    const float* nx = nxyz + ((size_t)(b * S_ + s)) * 3;
#pragma unroll
    for (int j = 0; j < 3; ++j) {
        float h = X[(size_t)j * N_ + idx] - nx[j];
        const float* wr = WT + (size_t)(64 + j) * 64;
#pragma unroll
        for (int o = 0; o < 64; ++o) acc[o] = fmaf(h, wr[o], acc[o]);
    }
    ushort_t* yr = y + (size_t)m * 64;
#pragma unroll
    for (int v8 = 0; v8 < 8; ++v8) {
        us8 wv;
#pragma unroll
        for (int j = 0; j < 8; ++j) wv[j] = f2bf(acc[v8 * 8 + j]);
        *reinterpret_cast<us8*>(yr + v8 * 8) = wv;
        *reinterpret_cast<us8*>(sb + tid * RP + v8 * 8) = wv;
    }
    __syncthreads();
    if (tid < 128) {
        int c = tid & 63, half = tid >> 6;
        float sv = 0.0f, qv = 0.0f;
        int r0 = half * 128;
        for (int r = 0; r < 128; ++r) {
            float v = bf2f(sb[(r0 + r) * RP + c]);
            sv += v; qv = fmaf(v, v, qv);
        }
        ps[tid] = sv; pq[tid] = qv;
    }
    __syncthreads();
    if (tid < 64) {
        atomicAdd(&sums[tid], ps[tid] + ps[tid + 64]);
        atomicAdd(&sums[128 + tid], pq[tid] + pq[tid + 64]);
    }
}

// ---------- 6b. layers 2/3: 32 ch/thread + inline BN finalize + fused stats ----------
__global__ __launch_bounds__(256, 8)
void layer32_kernel(const ushort_t* __restrict__ xin,
                    const float* __restrict__ WT,     // [64][COtot]
                    const float* __restrict__ bias,   // [COtot]
                    const float* __restrict__ sums_in,// prev layer stats
                    const float* __restrict__ g,
                    const float* __restrict__ be,
                    ushort_t* __restrict__ y,         // [M][COtot]
                    int COtot,
                    float* __restrict__ sums) {       // out stats
    constexpr int RP = 40;                 // padded row (ushorts), 80 B = 5*16
    __shared__ ushort_t sb[256 * RP];      // 20 KB
    __shared__ float ps[64], pq[64];
    __shared__ float s_a[64], s_sh[64];
    int tid = threadIdx.x;
    // inline finalize (identical expressions to the old finalize kernel)
    if (tid < 64) {
        float mean = sums_in[tid] * (1.0f / (float)M_);
        float var = sums_in[128 + tid] * (1.0f / (float)M_) - mean * mean;
        float a = g[tid] / sqrtf(var + EPS_);
        s_a[tid] = a;
        s_sh[tid] = be[tid] - mean * a;
    }
    __syncthreads();

    int m = blockIdx.x * 256 + tid;
    int os = blockIdx.y * 32;
    float acc[32];
#pragma unroll
    for (int o = 0; o < 32; ++o) acc[o] = bias[os + o];

    const ushort_t* row = xin + (size_t)m * 64;
#pragma unroll
    for (int c8 = 0; c8 < 8; ++c8) {
        us8 v = *reinterpret_cast<const us8*>(row + c8 * 8);
#pragma unroll
        for (int j = 0; j < 8; ++j) {
            int c = c8 * 8 + j;
            float h = fmaxf(fmaf(s_a[c], bf2f(v[j]), s_sh[c]), 0.0f);
            const float* wr = WT + (size_t)c * COtot + os;
#pragma unroll
            for (int o = 0; o < 32; ++o) acc[o] = fmaf(h, wr[o], acc[o]);
        }
    }
    ushort_t* yr = y + (size_t)m * COtot + os;
#pragma unroll
    for (int v8 = 0; v8 < 4; ++v8) {
        us8 wv;
#pragma unroll
        for (int j = 0; j < 8; ++j) wv[j] = f2bf(acc[v8 * 8 + j]);
        *reinterpret_cast<us8*>(yr + v8 * 8) = wv;
        *reinterpret_cast<us8*>(sb + tid * RP + v8 * 8) = wv;
    }
    __syncthreads();
    if (tid < 64) {
        int c = tid & 31, half = tid >> 5;
        float sv = 0.0f, qv = 0.0f;
        int r0 = half * 128;
        for (int r = 0; r < 128; ++r) {
            float v = bf2f(sb[(r0 + r) * RP + c]);
            sv += v; qv = fmaf(v, v, qv);
        }
        ps[tid] = sv; pq[tid] = qv;
    }
    __syncthreads();
    if (tid < 32) {
        int cg = os + tid;
        atomicAdd(&sums[cg], ps[tid] + ps[tid + 32]);
        atomicAdd(&sums[128 + cg], pq[tid] + pq[tid + 32]);
    }
}

// ---------- 9. final: inline BN finalize + max over K + relu ----------
__global__ __launch_bounds__(256)
void final_max(const ushort_t* __restrict__ x3, const float* __restrict__ sums,
               const float* __restrict__ g, const float* __restrict__ be,
               float* __restrict__ out1) {
    __shared__ float s_a[128], s_sh[128];
    int t = threadIdx.x;
    if (t < 128) {
        float mean = sums[t] * (1.0f / (float)M_);
        float var = sums[128 + t] * (1.0f / (float)M_) - mean * mean;
        float a = g[t] / sqrtf(var + EPS_);
        s_a[t] = a;
        s_sh[t] = be[t] - mean * a;
    }
    __syncthreads();
    int gw = blockIdx.x * 4 + (t >> 6);
    if (gw >= B_ * S_) return;
    int lane = t & 63;
    int b = gw / S_, s = gw % S_;
    int c0 = lane * 2;
    float a0 = s_a[c0], k0 = s_sh[c0];
    float a1 = s_a[c0 + 1], k1 = s_sh[c0 + 1];
    const ushort_t* base = x3 + (size_t)gw * K_ * 128;
    float m0 = -1e30f, m1 = -1e30f;
#pragma unroll 8
    for (int k = 0; k < K_; ++k) {
        uint_t v = *reinterpret_cast<const uint_t*>(base + k * 128 + c0);
        float f0 = fmaf(bf2f((ushort_t)(v & 0xffff)), a0, k0);
        float f1 = fmaf(bf2f((ushort_t)(v >> 16)), a1, k1);
        m0 = fmaxf(m0, f0); m1 = fmaxf(m1, f1);
    }
    out1[((size_t)b * 128 + c0) * S_ + s] = fmaxf(m0, 0.0f);
    out1[((size_t)b * 128 + c0 + 1) * S_ + s] = fmaxf(m1, 0.0f);
}

// ---------- launch ----------
extern "C" void kernel_launch(void* const* d_in, const int* in_sizes, int n_in,
                              void* d_out, int out_size, void* d_ws, size_t ws_size,
                              hipStream_t stream) {
    const float* xyz = (const float*)d_in[0];
    const float* pts = (const float*)d_in[1];
    const float* w0 = (const float*)d_in[2];
    const float* b0 = (const float*)d_in[3];
    const float* g0 = (const float*)d_in[4];
    const float* be0 = (const float*)d_in[5];
    const float* w1 = (const float*)d_in[6];
    const float* b1 = (const float*)d_in[7];
    const float* g1 = (const float*)d_in[8];
    const float* be1 = (const float*)d_in[9];
    const float* w2 = (const float*)d_in[10];
    const float* b2 = (const float*)d_in[11];
    const float* g2 = (const float*)d_in[12];
    const float* be2 = (const float*)d_in[13];

    float* out0 = (float*)d_out;
    float* out1 = out0 + (size_t)B_ * 3 * S_;

    char* ws = (char*)d_ws;
    float*    nxyz  = (float*)(ws + 32768);           // 96 KB
    int*      gi    = (int*)(ws + 131072);            // 1 MB
    float*    stats = (float*)(ws + 1179648);         // 3 KB
    float*    wt    = (float*)(ws + 1185792);         // 65 KB
    ushort_t* ptT   = (ushort_t*)(ws + 2097152);      // 8 MB
    ushort_t* xA    = (ushort_t*)(ws + 10485760);     // 67 MB (x1 stride 64, later x3 stride 128)
    ushort_t* xB    = (ushort_t*)(ws + 77594624);     // 33.5 MB (x2)

    // fps (8 blocks) + transpose (256) + wt/zero (1): independent work overlaps fps
    fps_fused<<<265, 1024, 0, stream>>>(xyz, pts, w0, w1, w2, nxyz, out0, ptT, wt, stats);
    ballq_kernel<<<(B_ * S_) / 4, 256, 0, stream>>>(xyz, nxyz, gi);

    // layer 1 (fused gather + stats) -> xA (stride 64)
    layer1_kernel<<<M_ / 256, 256, 0, stream>>>(ptT, xyz, nxyz, gi, wt, b0, xA, stats + 0);

    // layer 2 (+inline finalize of layer1 stats) -> xB
    layer32_kernel<<<dim3(M_ / 256, 2), 256, 0, stream>>>(
        xA, wt + 67 * 64, b1, stats + 0, g0, be0, xB, 64, stats + 256);

    // layer 3 (+inline finalize of layer2 stats) -> xA (stride 128)
    layer32_kernel<<<dim3(M_ / 256, 4), 256, 0, stream>>>(
        xB, wt + 67 * 64 + 64 * 64, b2, stats + 256, g1, be1, xA, 128, stats + 512);

    // final max (+inline finalize of layer3 stats)
    final_max<<<(B_ * S_) / 4, 256, 0, stream>>>(xA, stats + 512, g2, be2, out1);
}

// Round 15
// 1187.062 us; speedup vs baseline: 1.0933x; 1.0933x over previous
//
#include <hip/hip_runtime.h>

typedef unsigned short ushort_t;
typedef unsigned int uint_t;
typedef unsigned long long u64_t;
typedef unsigned short us8 __attribute__((ext_vector_type(8)));

constexpr int B_ = 8, N_ = 8192, S_ = 1024, K_ = 32;
constexpr int M_ = B_ * S_ * K_;          // 262144
constexpr float R2_ = 0.04f;
constexpr float EPS_ = 1e-5f;

// ---------- helpers ----------
__device__ __forceinline__ float bf2f(ushort_t u) {
    union { uint_t i; float f; } v; v.i = ((uint_t)u) << 16; return v.f;
}
__device__ __forceinline__ ushort_t f2bf(float f) {
    union { float f; uint_t i; } v; v.f = f;
    uint_t i = v.i;
    uint_t r = (i + 0x7FFFu + ((i >> 16) & 1u)) >> 16;   // RNE
    return (ushort_t)r;
}

// f32 DPP max helper (2 inst/stage). bound_ctrl=true -> OOB lanes read 0,
// safe because all reduced values are >= 0.
template<int C> __device__ __forceinline__ float dmaxf(float v) {
    int o = __builtin_amdgcn_mov_dpp(__float_as_int(v), C, 0xf, 0xf, true);
    return fmaxf(v, __int_as_float(o));
}

// ---------- 1. fused: FPS (blocks 0..7) + transpose (8..263) + wt/zero (264) ----------
// FPS: R13 structure (measured optimum). Thread t owns points [8t,8t+8) =>
// lane order == index order == wave order; max value + first occurrence ==
// jnp.argmax over distances in the reference association order.
__global__ __launch_bounds__(1024)
void fps_fused(const float* __restrict__ xyz, const float* __restrict__ pts,
               const float* __restrict__ w0, const float* __restrict__ w1,
               const float* __restrict__ w2,
               float* __restrict__ nxyz, float* __restrict__ out0,
               ushort_t* __restrict__ ptT, float* __restrict__ wt,
               float* __restrict__ stats) {
    __shared__ __align__(16) char smem[131072 + 4096 + 64 + 16];
    const int bx = blockIdx.x, t = threadIdx.x;

    if (bx >= 8) {
        if (bx == 264) {
            // zero stats + transpose weights W[co][ci] -> WT[ci][co]
            if (t < 768) stats[t] = 0.0f;
#pragma unroll
            for (int l = 0; l < 3; ++l) {
                const float* w = l == 0 ? w0 : (l == 1 ? w1 : w2);
                int CI = (l == 0) ? 67 : 64;
                int CO = (l == 2) ? 128 : 64;
                float* dst = wt + (l == 0 ? 0 : (l == 1 ? 67 * 64 : 67 * 64 + 64 * 64));
                for (int i = t; i < CI * CO; i += 1024) {
                    int c = i / CO, o = i % CO;
                    dst[c * CO + o] = w[o * CI + c];
                }
            }
            return;
        }
        // transpose: 4 tiles per block (group g handles tile tau)
        int g = t >> 8, lt = t & 255;
        int tau = (bx - 8) * 4 + g;
        int b = tau >> 7, n0 = (tau & 127) * 64;
        int tc = lt & 63, tr = lt >> 6;
        ushort_t* tile = (ushort_t*)(smem + g * 8448);   // 64*66*2 B
        const float* src = pts + (size_t)b * 64 * N_;
#pragma unroll
        for (int i = 0; i < 16; ++i) {
            int c = i * 4 + tr;
            tile[c * 66 + tc] = f2bf(src[(size_t)c * N_ + n0 + tc]);
        }
        __syncthreads();
#pragma unroll
        for (int i = 0; i < 16; ++i) {
            int nr = i * 4 + tr;
            ptT[((size_t)b * N_ + n0 + nr) * 64 + tc] = tile[tc * 66 + nr];
        }
        return;
    }

    // ---------------- FPS path (R13 structure) ----------------
    constexpr int T = 1024, P = N_ / T;    // 8 points per thread
    const int b = bx;
    const int lane = t & 63, w = t >> 6;   // 16 waves
    const float* X = xyz + (size_t)b * 3 * N_;

    float4* sxyz = (float4*)smem;                    // 128 KB
    int*    sidx = (int*)(smem + 131072);            // 4 KB
    float*  rv   = (float*)(smem + 131072 + 4096);   // 64 B
    int*    sfar = (int*)(smem + 131072 + 4096 + 64);

    // coalesced global -> LDS
#pragma unroll
    for (int i = 0; i < P; ++i) {
        int n = t + i * T;
        sxyz[n] = make_float4(X[n], X[N_ + n], X[2 * N_ + n], 0.0f);
    }
    if (t == 0) sidx[0] = 0;
    __syncthreads();

    // chunked re-read, rotated to cut bank conflicts 64-way -> 8-way
    float px[P], py[P], pz[P], dist[P];
#pragma unroll
    for (int i = 0; i < P; ++i) {
        int j = (i + t) & (P - 1);
        float4 v = sxyz[t * P + j];
        px[j] = v.x; py[j] = v.y; pz[j] = v.z;
        dist[j] = 1e10f;
    }
    float4 cc = sxyz[0];
    float cx = cc.x, cy = cc.y, cz = cc.z;

    for (int s = 0; s < S_; ++s) {
        // exact reference order: ((dx*dx + dy*dy) + dz*dz), unfused
#pragma unroll
        for (int i = 0; i < P; ++i) {
            float dx = __fsub_rn(px[i], cx);
            float dy = __fsub_rn(py[i], cy);
            float dz = __fsub_rn(pz[i], cz);
            float d = __fadd_rn(__fadd_rn(__fmul_rn(dx, dx), __fmul_rn(dy, dy)), __fmul_rn(dz, dz));
            dist[i] = fminf(dist[i], d);
        }
        // in-thread tree max (value only)
        float a0 = fmaxf(dist[0], dist[4]);
        float a1 = fmaxf(dist[1], dist[5]);
        float a2 = fmaxf(dist[2], dist[6]);
        float a3 = fmaxf(dist[3], dist[7]);
        float lmax = fmaxf(fmaxf(a0, a1), fmaxf(a2, a3));
        // wave max via DPP, result in lane 63
        float m = lmax;
        m = dmaxf<0x111>(m);   // row_shr:1
        m = dmaxf<0x112>(m);   // row_shr:2
        m = dmaxf<0x114>(m);   // row_shr:4
        m = dmaxf<0x118>(m);   // row_shr:8
        m = dmaxf<0x142>(m);   // row_bcast:15
        m = dmaxf<0x143>(m);   // row_bcast:31
        if (lane == 63) rv[w] = m;
        __syncthreads();                       // barrier 1

        // cross-wave max: 16-periodic data, ror 1,2,4,8 covers the 16 values
        float kv0 = rv[lane & 15];
        float kv = kv0;
        kv = dmaxf<0x121>(kv);  // row_ror:1
        kv = dmaxf<0x122>(kv);  // row_ror:2
        kv = dmaxf<0x124>(kv);  // row_ror:4
        kv = dmaxf<0x128>(kv);  // row_ror:8
        float gmax = kv;
        u64_t wm = __ballot(kv0 == gmax);
        int first_w = __builtin_ctzll(wm);     // < 16

        if (w == first_w) {                    // wave-uniform branch
            u64_t lm = __ballot(lmax == gmax);
            int L = __builtin_ctzll(lm);       // lowest lane = lowest index
            if (lane == L) {
                int fi = 0;
#pragma unroll
                for (int i = P - 1; i >= 0; --i)
                    if (dist[i] == gmax) fi = i;   // lowest i wins
                int nf = t * P + fi;
                *sfar = nf;
                if (s + 1 < S_) sidx[s + 1] = nf;
            }
        }
        __syncthreads();                       // barrier 2
        int nf = *sfar;
        float4 c = sxyz[nf];                   // single b128 LDS broadcast
        cx = c.x; cy = c.y; cz = c.z;
    }

    // fused gather: nxyz + output 0 straight from LDS
    __syncthreads();
    {
        int s = t;                             // T == S_
        int idx = sidx[s];
        float4 c = sxyz[idx];
        size_t base = ((size_t)b * S_ + s) * 3;
        nxyz[base + 0] = c.x; nxyz[base + 1] = c.y; nxyz[base + 2] = c.z;
        out0[((size_t)b * 3 + 0) * S_ + s] = c.x;
        out0[((size_t)b * 3 + 1) * S_ + s] = c.y;
        out0[((size_t)b * 3 + 2) * S_ + s] = c.z;
    }
}

// ---------- 3. ball query: one wave per query, ordered ballot compaction ----------
__global__ __launch_bounds__(256)
void ballq_kernel(const float* __restrict__ xyz, const float* __restrict__ nxyz,
                  int* __restrict__ gi) {
    int wid = (blockIdx.x * 256 + threadIdx.x) >> 6;
    int lane = threadIdx.x & 63;
    if (wid >= B_ * S_) return;
    int b = wid / S_;
    const float* X = xyz + (size_t)b * 3 * N_;
    float nx = nxyz[(size_t)wid * 3 + 0];
    float ny = nxyz[(size_t)wid * 3 + 1];
    float nz = nxyz[(size_t)wid * 3 + 2];
    float snew = __fadd_rn(__fadd_rn(__fmul_rn(nx, nx), __fmul_rn(ny, ny)), __fmul_rn(nz, nz));
    int cnt = 0; int firstn = 0;
    int* out = gi + (size_t)wid * K_;
    for (int c0 = 0; c0 < N_; c0 += 64) {
        int n = c0 + lane;
        float xx = X[n], xy = X[N_ + n], xz = X[2 * N_ + n];
        float sxn = __fadd_rn(__fadd_rn(__fmul_rn(xx, xx), __fmul_rn(xy, xy)), __fmul_rn(xz, xz));
        float dot = __fadd_rn(__fadd_rn(__fmul_rn(nx, xx), __fmul_rn(ny, xy)), __fmul_rn(nz, xz));
        float sq = __fsub_rn(__fadd_rn(snew, sxn), __fmul_rn(2.0f, dot));
        bool inr = !(sq > R2_);
        unsigned long long mask = __ballot(inr);
        if (cnt == 0 && mask) firstn = c0 + __builtin_ctzll(mask);
        int rank = __popcll(mask & ((1ull << lane) - 1ull));
        if (inr && cnt + rank < K_) out[cnt + rank] = n;
        cnt += (int)__popcll(mask);
        if (cnt >= K_) break;
    }
    if (cnt < K_ && lane >= cnt && lane < K_) out[lane] = firstn;
}

// ---------- 6a. layer 1: fused gather + fused stats ----------
__global__ __launch_bounds__(256)
void layer1_kernel(const ushort_t* __restrict__ ptT,
                   const float* __restrict__ xyz,
                   const float* __restrict__ nxyz,
                   const int* __restrict__ gi,
                   const float* __restrict__ WT,     // [67][64]
                   const float* __restrict__ bias,   // [64]
                   ushort_t* __restrict__ y,         // [M][64]
                   float* __restrict__ sums) {       // [64]=sum, [128+..]=sumsq
    constexpr int RP = 72;                 // padded row (ushorts), 144 B = 9*16
    __shared__ ushort_t sb[256 * RP];      // 36 KB
    __shared__ float ps[128], pq[128];
    int tid = threadIdx.x;
    int m = blockIdx.x * 256 + tid;
    float acc[64];
#pragma unroll
    for (int o = 0; o < 64; ++o) acc[o] = bias[o];

    int idx = gi[m];
    int b = m >> 15;                       // m / (S*K)
    const ushort_t* row = ptT + ((size_t)b * N_ + idx) * 64;
#pragma unroll
    for (int c8 = 0; c8 < 8; ++c8) {
        us8 v = *reinterpret_cast<const us8*>(row + c8 * 8);
#pragma unroll
        for (int j = 0; j < 8; ++j) {
            int c = c8 * 8 + j;
            float h = bf2f(v[j]);
            const float* wr = WT + (size_t)c * 64;
#pragma unroll
            for (int o = 0; o < 64; ++o) acc[o] = fmaf(h, wr[o], acc[o]);
        }
    }
    int s = (m >> 5) & (S_ - 1);
    const float* X = xyz + (size_t)b * 3 * N_;
    const float* nx = nxyz + ((size_t)(b * S_ + s)) * 3;
#pragma unroll
    for (int j = 0; j < 3; ++j) {
        float h = X[(size_t)j * N_ + idx] - nx[j];
        const float* wr = WT + (size_t)(64 + j) * 64;
#pragma unroll
        for (int o = 0; o < 64; ++o) acc[o] = fmaf(h, wr[o], acc[o]);
    }
    ushort_t* yr = y + (size_t)m * 64;
#pragma unroll
    for (int v8 = 0; v8 < 8; ++v8) {
        us8 wv;
#pragma unroll
        for (int j = 0; j < 8; ++j) wv[j] = f2bf(acc[v8 * 8 + j]);
        *reinterpret_cast<us8*>(yr + v8 * 8) = wv;
        *reinterpret_cast<us8*>(sb + tid * RP + v8 * 8) = wv;
    }
    __syncthreads();
    if (tid < 128) {
        int c = tid & 63, half = tid >> 6;
        float sv = 0.0f, qv = 0.0f;
        int r0 = half * 128;
        for (int r = 0; r < 128; ++r) {
            float v = bf2f(sb[(r0 + r) * RP + c]);
            sv += v; qv = fmaf(v, v, qv);
        }
        ps[tid] = sv; pq[tid] = qv;
    }
    __syncthreads();
    if (tid < 64) {
        atomicAdd(&sums[tid], ps[tid] + ps[tid + 64]);
        atomicAdd(&sums[128 + tid], pq[tid] + pq[tid + 64]);
    }
}

// ---------- 6b. layers 2/3: 32 ch/thread + inline BN finalize + fused stats ----------
// DO_MAX=1 (layer 3): skip the y-write; instead reduce max over each K-group
// (32 rows) in LDS and emit xmax[gw][128]. Valid because a=g/sqrt(var+eps)>0
// (g==1) and fmaf/relu are monotone in x => max commutes bitwise.
template<int DO_MAX>
__global__ __launch_bounds__(256, 8)
void layer32_kernel(const ushort_t* __restrict__ xin,
                    const float* __restrict__ WT,     // [64][COtot]
                    const float* __restrict__ bias,   // [COtot]
                    const float* __restrict__ sums_in,// prev layer stats
                    const float* __restrict__ g,
                    const float* __restrict__ be,
                    ushort_t* __restrict__ y,         // [M][COtot] (DO_MAX=0)
                    float* __restrict__ xmax,         // [B*S][128]  (DO_MAX=1)
                    int COtot,
                    float* __restrict__ sums) {       // out stats
    constexpr int RP = 40;                 // padded row (ushorts), 80 B = 5*16
    __shared__ ushort_t sb[256 * RP];      // 20 KB
    __shared__ float ps[64], pq[64];
    __shared__ float s_a[64], s_sh[64];
    int tid = threadIdx.x;
    // inline finalize (identical expressions to the old finalize kernel)
    if (tid < 64) {
        float mean = sums_in[tid] * (1.0f / (float)M_);
        float var = sums_in[128 + tid] * (1.0f / (float)M_) - mean * mean;
        float a = g[tid] / sqrtf(var + EPS_);
        s_a[tid] = a;
        s_sh[tid] = be[tid] - mean * a;
    }
    __syncthreads();

    int m = blockIdx.x * 256 + tid;
    int os = blockIdx.y * 32;
    float acc[32];
#pragma unroll
    for (int o = 0; o < 32; ++o) acc[o] = bias[os + o];

    const ushort_t* row = xin + (size_t)m * 64;
#pragma unroll
    for (int c8 = 0; c8 < 8; ++c8) {
        us8 v = *reinterpret_cast<const us8*>(row + c8 * 8);
#pragma unroll
        for (int j = 0; j < 8; ++j) {
            int c = c8 * 8 + j;
            float h = fmaxf(fmaf(s_a[c], bf2f(v[j]), s_sh[c]), 0.0f);
            const float* wr = WT + (size_t)c * COtot + os;
#pragma unroll
            for (int o = 0; o < 32; ++o) acc[o] = fmaf(h, wr[o], acc[o]);
        }
    }
#pragma unroll
    for (int v8 = 0; v8 < 4; ++v8) {
        us8 wv;
#pragma unroll
        for (int j = 0; j < 8; ++j) wv[j] = f2bf(acc[v8 * 8 + j]);
        if (!DO_MAX) {
            ushort_t* yr = y + (size_t)m * COtot + os;
            *reinterpret_cast<us8*>(yr + v8 * 8) = wv;
        }
        *reinterpret_cast<us8*>(sb + tid * RP + v8 * 8) = wv;
    }
    __syncthreads();
    if (DO_MAX) {
        // per (K-group, channel) max over 32 rows; 8 groups x 32 ch = 256 thr
        int gq = tid >> 5, c = tid & 31;
        float mv = -1e30f;
        int r0 = gq * 32;
#pragma unroll 8
        for (int r = 0; r < 32; ++r) mv = fmaxf(mv, bf2f(sb[(r0 + r) * RP + c]));
        xmax[((size_t)(blockIdx.x * 8 + gq)) * 128 + os + c] = mv;
    }
    if (tid < 64) {
        int c = tid & 31, half = tid >> 5;
        float sv = 0.0f, qv = 0.0f;
        int r0 = half * 128;
        for (int r = 0; r < 128; ++r) {
            float v = bf2f(sb[(r0 + r) * RP + c]);
            sv += v; qv = fmaf(v, v, qv);
        }
        ps[tid] = sv; pq[tid] = qv;
    }
    __syncthreads();
    if (tid < 64) {
        int cg = os + (tid & 31);
        if (tid < 32) {
            atomicAdd(&sums[cg], ps[tid] + ps[tid + 32]);
            atomicAdd(&sums[128 + cg], pq[tid] + pq[tid + 32]);
        }
    }
}

// ---------- 9. final: inline BN finalize + affine/relu on precomputed maxes ----------
__global__ __launch_bounds__(256)
void final_max(const float* __restrict__ xmax, const float* __restrict__ sums,
               const float* __restrict__ g, const float* __restrict__ be,
               float* __restrict__ out1) {
    __shared__ float s_a[128], s_sh[128];
    int t = threadIdx.x;
    if (t < 128) {
        float mean = sums[t] * (1.0f / (float)M_);
        float var = sums[128 + t] * (1.0f / (float)M_) - mean * mean;
        float a = g[t] / sqrtf(var + EPS_);
        s_a[t] = a;
        s_sh[t] = be[t] - mean * a;
    }
    __syncthreads();
    int gw = blockIdx.x * 4 + (t >> 6);
    if (gw >= B_ * S_) return;
    int lane = t & 63;
    int b = gw / S_, s = gw % S_;
    int c0 = lane * 2;
    float v0 = xmax[(size_t)gw * 128 + c0];
    float v1 = xmax[(size_t)gw * 128 + c0 + 1];
    float f0 = fmaf(v0, s_a[c0], s_sh[c0]);
    float f1 = fmaf(v1, s_a[c0 + 1], s_sh[c0 + 1]);
    out1[((size_t)b * 128 + c0) * S_ + s] = fmaxf(f0, 0.0f);
    out1[((size_t)b * 128 + c0 + 1) * S_ + s] = fmaxf(f1, 0.0f);
}

// ---------- launch ----------
extern "C" void kernel_launch(void* const* d_in, const int* in_sizes, int n_in,
                              void* d_out, int out_size, void* d_ws, size_t ws_size,
                              hipStream_t stream) {
    const float* xyz = (const float*)d_in[0];
    const float* pts = (const float*)d_in[1];
    const float* w0 = (const float*)d_in[2];
    const float* b0 = (const float*)d_in[3];
    const float* g0 = (const float*)d_in[4];
    const float* be0 = (const float*)d_in[5];
    const float* w1 = (const float*)d_in[6];
    const float* b1 = (const float*)d_in[7];
    const float* g1 = (const float*)d_in[8];
    const float* be1 = (const float*)d_in[9];
    const float* w2 = (const float*)d_in[10];
    const float* b2 = (const float*)d_in[11];
    const float* g2 = (const float*)d_in[12];
    const float* be2 = (const float*)d_in[13];

    float* out0 = (float*)d_out;
    float* out1 = out0 + (size_t)B_ * 3 * S_;

    char* ws = (char*)d_ws;
    float*    nxyz  = (float*)(ws + 32768);           // 96 KB
    int*      gi    = (int*)(ws + 131072);            // 1 MB
    float*    stats = (float*)(ws + 1179648);         // 3 KB
    float*    wt    = (float*)(ws + 1185792);         // 65 KB
    ushort_t* ptT   = (ushort_t*)(ws + 2097152);      // 8 MB
    ushort_t* xA    = (ushort_t*)(ws + 10485760);     // 33.5 MB (x1, stride 64)
    float*    xmax  = (float*)(ws + 10485760);        // 4 MB (aliases xA; xA dead
                                                      //  after layer2 consumes it)
    ushort_t* xB    = (ushort_t*)(ws + 77594624);     // 33.5 MB (x2)

    // fps (8 blocks) + transpose (256) + wt/zero (1): independent work overlaps fps
    fps_fused<<<265, 1024, 0, stream>>>(xyz, pts, w0, w1, w2, nxyz, out0, ptT, wt, stats);
    ballq_kernel<<<(B_ * S_) / 4, 256, 0, stream>>>(xyz, nxyz, gi);

    // layer 1 (fused gather + stats) -> xA (stride 64)
    layer1_kernel<<<M_ / 256, 256, 0, stream>>>(ptT, xyz, nxyz, gi, wt, b0, xA, stats + 0);

    // layer 2 (+inline finalize of layer1 stats) -> xB
    layer32_kernel<0><<<dim3(M_ / 256, 2), 256, 0, stream>>>(
        xA, wt + 67 * 64, b1, stats + 0, g0, be0, xB, nullptr, 64, stats + 256);

    // layer 3 (+inline finalize of layer2 stats) -> xmax only (max over K fused)
    layer32_kernel<1><<<dim3(M_ / 256, 4), 256, 0, stream>>>(
        xB, wt + 67 * 64 + 64 * 64, b2, stats + 256, g1, be1, nullptr, xmax, 128, stats + 512);

    // final: affine+relu on the 4 MB max buffer (+inline finalize of layer3 stats)
    final_max<<<(B_ * S_) / 4, 256, 0, stream>>>(xmax, stats + 512, g2, be2, out1);
}